// Round 7
// baseline (557.019 us; speedup 1.0000x reference)
//
#include <hip/hip_runtime.h>

namespace {

constexpr int kN  = 20000;
constexpr int kE  = 80000;
constexpr int kIn = 64;
constexpr int kH  = 32;
constexpr int kEA = 32;
constexpr int kT  = 64;
constexpr int kL  = 3;
constexpr float kEps = 1e-5f;

typedef __attribute__((ext_vector_type(8))) short bf16x8;
typedef __attribute__((ext_vector_type(4))) float f32x4;
typedef __attribute__((ext_vector_type(4))) unsigned short u16x4;

__device__ inline unsigned short f2bf(float f) {
  unsigned u = __builtin_bit_cast(unsigned, f);
  unsigned r = (u + 0x7fff + ((u >> 16) & 1)) >> 16;  // RNE
  return (unsigned short)r;
}
__device__ inline float bf2f(unsigned short s) {
  unsigned u = ((unsigned)s) << 16;
  return __builtin_bit_cast(float, u);
}

// ---------------- edge->dst grouping: hist / scan / place ----------------
__global__ __launch_bounds__(256) void hist_dst(const int* __restrict__ ei,
                                                int* __restrict__ cnt) {
  const int e = blockIdx.x * 256 + threadIdx.x;
  if (e < kE) atomicAdd(&cnt[ei[kE + e]], 1);
}

__global__ __launch_bounds__(1024) void scan_nodes(const int* __restrict__ cnt,
                                                   int* __restrict__ off,
                                                   int* __restrict__ cursor) {
  __shared__ int buf[1024];
  __shared__ int carry_s;
  const int tid = threadIdx.x;
  if (tid == 0) carry_s = 0;
  __syncthreads();
  for (int c = 0; c < (kN + 1023) / 1024; ++c) {
    const int i = c * 1024 + tid;
    const int v = (i < kN) ? cnt[i] : 0;
    buf[tid] = v;
    __syncthreads();
    for (int s = 1; s < 1024; s <<= 1) {
      int t = 0;
      if (tid >= s) t = buf[tid - s];
      __syncthreads();
      buf[tid] += t;
      __syncthreads();
    }
    const int excl = buf[tid] - v + carry_s;
    if (i < kN) { off[i] = excl; cursor[i] = excl; }
    __syncthreads();
    if (tid == 0) carry_s += buf[1023];
    __syncthreads();
  }
}

__global__ __launch_bounds__(256) void place_edges(const int* __restrict__ ei,
                                                   int* __restrict__ cursor,
                                                   int* __restrict__ pos) {
  const int e = blockIdx.x * 256 + threadIdx.x;
  if (e < kE) pos[e] = atomicAdd(&cursor[ei[kE + e]], 1);
}

// ---- pack Wm[l] f32[32][1024] -> B-fragment-ordered bf16: frag[l][ct][lane][8]
__global__ __launch_bounds__(256) void pack_w(const float* __restrict__ emW,
                                              unsigned short* __restrict__ wbf) {
  const int idx = blockIdx.x * 256 + threadIdx.x;
  if (idx >= kL * 64 * 64) return;
  const int lane = idx & 63, ct = (idx >> 6) & 63, l = idx >> 12;
  const int k0 = (lane >> 4) * 8, c = ct * 16 + (lane & 15);
  const float* W = emW + (size_t)l * kEA * kH * kH;
  unsigned out[4];
#pragma unroll
  for (int p = 0; p < 4; ++p) {
    unsigned lo = f2bf(W[(size_t)(k0 + 2 * p) * (kH * kH) + c]);
    unsigned hi = f2bf(W[(size_t)(k0 + 2 * p + 1) * (kH * kH) + c]);
    out[p] = lo | (hi << 16);
  }
  *reinterpret_cast<uint4*>(wbf + (size_t)idx * 8) =
      make_uint4(out[0], out[1], out[2], out[3]);
}

// ---------------- h = x @ initW + initb (64-thr blocks) ----------------
__global__ __launch_bounds__(64) void init_proj(
    const float* __restrict__ x, const float* __restrict__ W,
    const float* __restrict__ b, float* __restrict__ h) {
  __shared__ float Wl[kIn * kH];
  __shared__ float bl[kH];
  const int tid = threadIdx.x;
  {
    const float4* Ws = reinterpret_cast<const float4*>(W);
    float4* Wd = reinterpret_cast<float4*>(Wl);
    for (int j = tid; j < kIn * kH / 4; j += 64) Wd[j] = Ws[j];
  }
  if (tid < kH) bl[tid] = b[tid];
  __syncthreads();
  const int node = blockIdx.x * 64 + tid;
  if (node >= kN) return;
  float xr[kIn];
  const float4* xp = reinterpret_cast<const float4*>(x + (size_t)node * kIn);
#pragma unroll
  for (int k4 = 0; k4 < kIn / 4; ++k4) {
    float4 v = xp[k4];
    xr[k4 * 4 + 0] = v.x; xr[k4 * 4 + 1] = v.y;
    xr[k4 * 4 + 2] = v.z; xr[k4 * 4 + 3] = v.w;
  }
  float* hp = h + (size_t)node * kH;
#pragma unroll
  for (int o = 0; o < kH; ++o) {
    float acc = bl[o];
#pragma unroll
    for (int k = 0; k < kIn; ++k) acc = fmaf(xr[k], Wl[k * kH + o], acc);
    hp[o] = acc;
  }
}

// ------- MFMA edge MLP + message -> msg_buf[pos[e]] (8 waves x 4 i) -------
constexpr int EB = 64;  // edges per block (kE = 1250*64 exactly)
constexpr int AP = 40;  // attr/h LDS row pitch in ushorts (80 B)
constexpr int MP = 36;  // msg LDS row pitch in f32 (144 B)
__global__ __launch_bounds__(512, 6) void edge_msg_mfma(
    const float* __restrict__ attr, const int* __restrict__ ei,
    const int* __restrict__ pos, const float* __restrict__ h,
    const unsigned short* __restrict__ wbf, const float* __restrict__ bm,
    float* __restrict__ msg_buf) {
  __shared__ unsigned short attr_s[EB * AP];  // 5 KB
  __shared__ unsigned short h_s[EB * AP];     // 5 KB
  __shared__ float msg_s[EB * MP];            // 9 KB
  const int tid = threadIdx.x;
  const int base = blockIdx.x * EB;

  for (int j = tid; j < EB * MP; j += 512) msg_s[j] = 0.f;

  // stage: 8 threads per edge, 4 attr + 4 h floats each
  {
    const int el = tid >> 3, p = tid & 7;
    const int e = base + el;
    const int src = ei[e];
    float4 a0 = reinterpret_cast<const float4*>(attr + (size_t)e * kEA)[p];
    float4 h0 = reinterpret_cast<const float4*>(h + (size_t)src * kH)[p];
    uint2 pa = make_uint2(f2bf(a0.x) | ((unsigned)f2bf(a0.y) << 16),
                          f2bf(a0.z) | ((unsigned)f2bf(a0.w) << 16));
    uint2 ph = make_uint2(f2bf(h0.x) | ((unsigned)f2bf(h0.y) << 16),
                          f2bf(h0.z) | ((unsigned)f2bf(h0.w) << 16));
    *reinterpret_cast<uint2*>(attr_s + el * AP + p * 4) = pa;
    *reinterpret_cast<uint2*>(h_s + el * AP + p * 4) = ph;
  }

  const int lane = tid & 63;
  const int w = tid >> 6;    // 0..7, owns i in [4w, 4w+4)
  const int lr = lane & 15;  // A row / B,C col within tile
  const int lg = lane >> 4;  // k-chunk / C row-group

  bf16x8 Bf[8];
#pragma unroll
  for (int t = 0; t < 8; ++t)
    Bf[t] = *reinterpret_cast<const bf16x8*>(
        wbf + ((size_t)(w * 8 + t) * 64 + lane) * 8);
  float biasr[4][2];
#pragma unroll
  for (int il = 0; il < 4; ++il)
#pragma unroll
    for (int hh = 0; hh < 2; ++hh)
      biasr[il][hh] = bm[(w * 4 + il) * kH + hh * 16 + lr];

  int mypos = 0;
  if (tid < EB) mypos = pos[base + tid];

  __syncthreads();

#pragma unroll
  for (int eg = 0; eg < EB / 16; ++eg) {
    bf16x8 Af = *reinterpret_cast<const bf16x8*>(
        attr_s + (eg * 16 + lr) * AP + lg * 8);
    // h[edge=C-row][i=4w..4w+3], packed (convert on use)
    u16x4 hv[4];
#pragma unroll
    for (int r = 0; r < 4; ++r)
      hv[r] = *reinterpret_cast<const u16x4*>(
          h_s + (eg * 16 + lg * 4 + r) * AP + w * 4);
    float ma[4][2];
#pragma unroll
    for (int r = 0; r < 4; ++r) { ma[r][0] = 0.f; ma[r][1] = 0.f; }
#pragma unroll
    for (int il = 0; il < 4; ++il) {
#pragma unroll
      for (int hh = 0; hh < 2; ++hh) {
        f32x4 c;
        c[0] = biasr[il][hh]; c[1] = biasr[il][hh];
        c[2] = biasr[il][hh]; c[3] = biasr[il][hh];
        c = __builtin_amdgcn_mfma_f32_16x16x32_bf16(Af, Bf[il * 2 + hh], c,
                                                    0, 0, 0);
#pragma unroll
        for (int r = 0; r < 4; ++r)
          ma[r][hh] = fmaf(fmaxf(c[r], 0.f), bf2f(hv[r][il]), ma[r][hh]);
      }
    }
#pragma unroll
    for (int r = 0; r < 4; ++r)
#pragma unroll
      for (int hh = 0; hh < 2; ++hh)
        atomicAdd(&msg_s[(eg * 16 + lg * 4 + r) * MP + hh * 16 + lr],
                  ma[r][hh]);
  }
  __syncthreads();

  if (tid < EB) {
    float* mrow = msg_buf + (size_t)mypos * kH;
#pragma unroll
    for (int o4 = 0; o4 < kH / 4; ++o4)
      *reinterpret_cast<float4*>(mrow + o4 * 4) =
          *reinterpret_cast<const float4*>(msg_s + tid * MP + o4 * 4);
  }
}

// ------- wave-per-node segmented sum (unchanged) -------
__global__ __launch_bounds__(256) void agg_nodes(
    const float* __restrict__ msg, const int* __restrict__ off,
    const int* __restrict__ cnt, float* __restrict__ conv) {
  const int wid = (blockIdx.x * 256 + threadIdx.x) >> 6;
  const int lane = threadIdx.x & 63;
  const int col = lane & 31, half = lane >> 5;
  if (wid >= kN) return;
  const int s = off[wid], n = cnt[wid];
  float acc = 0.f;
  for (int j = half; j < n; j += 2)
    acc += msg[(size_t)(s + j) * kH + col];
  acc += __shfl_xor(acc, 32);
  if (half == 0) conv[(size_t)wid * kH + col] = acc;
}

// ------- conv += h@rootW + rootb + feature stats (64-thr blocks) -------
__global__ __launch_bounds__(64) void root_stats(
    const float* __restrict__ h, const float* __restrict__ W,
    const float* __restrict__ b, float* __restrict__ conv,
    float* __restrict__ stats) {
  __shared__ float Wl[kH * kH];
  __shared__ float bl[kH];
  __shared__ float buf[64 * (kH + 1)];
  const int tid = threadIdx.x;
  {
    const float4* Ws = reinterpret_cast<const float4*>(W);
    float4* Wd = reinterpret_cast<float4*>(Wl);
    for (int j = tid; j < kH * kH / 4; j += 64) Wd[j] = Ws[j];
  }
  if (tid < kH) bl[tid] = b[tid];
  __syncthreads();
  const int node = blockIdx.x * 64 + tid;
  const bool act = node < kN;
  float hr[kH];
  if (act) {
    const float4* hp = reinterpret_cast<const float4*>(h + (size_t)node * kH);
#pragma unroll
    for (int i4 = 0; i4 < kH / 4; ++i4) {
      float4 v = hp[i4];
      hr[i4 * 4 + 0] = v.x; hr[i4 * 4 + 1] = v.y;
      hr[i4 * 4 + 2] = v.z; hr[i4 * 4 + 3] = v.w;
    }
  } else {
#pragma unroll
    for (int i = 0; i < kH; ++i) hr[i] = 0.f;
  }
  float* cp = conv + (size_t)node * kH;
#pragma unroll
  for (int o = 0; o < kH; ++o) {
    float acc = 0.f;
    if (act) {
      acc = cp[o] + bl[o];
#pragma unroll
      for (int i = 0; i < kH; ++i) acc = fmaf(hr[i], Wl[i * kH + o], acc);
      cp[o] = acc;
    }
    buf[tid * (kH + 1) + o] = act ? acc : 0.f;
  }
  __syncthreads();
  if (tid < kH) {
    float s = 0.f, q = 0.f;
#pragma unroll 8
    for (int r = 0; r < 64; ++r) {
      float v = buf[r * (kH + 1) + tid];
      s += v;
      q = fmaf(v, v, q);
    }
    atomicAdd(stats + tid, s);
    atomicAdd(stats + kH + tid, q);
  }
}

// ---- hc = relu(graphnorm(conv))+h ; h = relu([h,hc]@transW + tb) (64-thr) ----
__global__ __launch_bounds__(64) void norm_trans(
    const float* __restrict__ conv, const float* __restrict__ stats,
    const float* __restrict__ gw, const float* __restrict__ gb,
    const float* __restrict__ gms, const float* __restrict__ Wt,
    const float* __restrict__ tb, float* __restrict__ h) {
  __shared__ float Wl[2 * kH * kH];
  __shared__ float tbl[kH];
  __shared__ float meanl[kH], rstdl[kH], gwl[kH], gbl[kH];
  const int tid = threadIdx.x;
  {
    const float4* Ws = reinterpret_cast<const float4*>(Wt);
    float4* Wd = reinterpret_cast<float4*>(Wl);
    for (int j = tid; j < 2 * kH * kH / 4; j += 64) Wd[j] = Ws[j];
  }
  if (tid < kH) {
    tbl[tid] = tb[tid];
    float m = stats[tid] * (1.f / kN);
    float q = stats[kH + tid] * (1.f / kN);
    float msv = gms[tid];
    float var = q - m * m * msv * (2.f - msv);
    meanl[tid] = msv * m;
    rstdl[tid] = rsqrtf(var + kEps);
    gwl[tid] = gw[tid];
    gbl[tid] = gb[tid];
  }
  __syncthreads();
  const int node = blockIdx.x * 64 + tid;
  if (node >= kN) return;
  float in_[2 * kH];
  const float* hp = h + (size_t)node * kH;
  const float* cp = conv + (size_t)node * kH;
#pragma unroll
  for (int i = 0; i < kH; ++i) in_[i] = hp[i];
#pragma unroll
  for (int o = 0; o < kH; ++o) {
    float v = cp[o];
    in_[kH + o] =
        fmaxf((v - meanl[o]) * rstdl[o] * gwl[o] + gbl[o], 0.f) + in_[o];
  }
  float* hw = h + (size_t)node * kH;
#pragma unroll
  for (int o = 0; o < kH; ++o) {
    float acc = tbl[o];
#pragma unroll
    for (int k = 0; k < 2 * kH; ++k) acc = fmaf(in_[k], Wl[k * kH + o], acc);
    hw[o] = fmaxf(acc, 0.f);
  }
}

// ---------- out = h @ finalW + finalb (+ stats), 64-thr blocks ----------
__global__ __launch_bounds__(64) void final_lin(
    const float* __restrict__ h, const float* __restrict__ W,
    const float* __restrict__ b, float* __restrict__ out,
    float* __restrict__ stats) {
  __shared__ float Wl[kH * kT];
  __shared__ float bl[kT];
  __shared__ float buf[64 * (kT + 1)];
  const int tid = threadIdx.x;
  {
    const float4* Ws = reinterpret_cast<const float4*>(W);
    float4* Wd = reinterpret_cast<float4*>(Wl);
    for (int j = tid; j < kH * kT / 4; j += 64) Wd[j] = Ws[j];
  }
  if (tid < kT) bl[tid] = b[tid];
  __syncthreads();
  const int node = blockIdx.x * 64 + tid;
  const bool act = node < kN;
  float hr[kH];
  if (act) {
    const float4* hp = reinterpret_cast<const float4*>(h + (size_t)node * kH);
#pragma unroll
    for (int i4 = 0; i4 < kH / 4; ++i4) {
      float4 v = hp[i4];
      hr[i4 * 4 + 0] = v.x; hr[i4 * 4 + 1] = v.y;
      hr[i4 * 4 + 2] = v.z; hr[i4 * 4 + 3] = v.w;
    }
  } else {
#pragma unroll
    for (int i = 0; i < kH; ++i) hr[i] = 0.f;
  }
  float* op = out + (size_t)node * kT;
#pragma unroll
  for (int o = 0; o < kT; ++o) {
    float acc = 0.f;
    if (act) {
      acc = bl[o];
#pragma unroll
      for (int i = 0; i < kH; ++i) acc = fmaf(hr[i], Wl[i * kT + o], acc);
      op[o] = acc;
    }
    buf[tid * (kT + 1) + o] = act ? acc : 0.f;
  }
  __syncthreads();
  if (tid < kT) {
    float s = 0.f, q = 0.f;
#pragma unroll 8
    for (int r = 0; r < 64; ++r) {
      float v = buf[r * (kT + 1) + tid];
      s += v;
      q = fmaf(v, v, q);
    }
    atomicAdd(stats + tid, s);
    atomicAdd(stats + kT + tid, q);
  }
}

// ------------- final graphnorm + relu (in place, 64-thr blocks) -------------
__global__ __launch_bounds__(64) void final_norm(
    const float* __restrict__ stats, const float* __restrict__ w,
    const float* __restrict__ b, const float* __restrict__ ms,
    float* __restrict__ out) {
  __shared__ float meanl[kT], rstdl[kT], wl2[kT], bl2[kT];
  const int tid = threadIdx.x;
  if (tid < kT) {
    float m = stats[tid] * (1.f / kN);
    float q = stats[kT + tid] * (1.f / kN);
    float msv = ms[tid];
    float var = q - m * m * msv * (2.f - msv);
    meanl[tid] = msv * m;
    rstdl[tid] = rsqrtf(var + kEps);
    wl2[tid] = w[tid];
    bl2[tid] = b[tid];
  }
  __syncthreads();
  const int node = blockIdx.x * 64 + tid;
  if (node >= kN) return;
  float* op = out + (size_t)node * kT;
#pragma unroll
  for (int o4 = 0; o4 < kT / 4; ++o4) {
    float4 v = *reinterpret_cast<const float4*>(op + o4 * 4);
    float r[4] = {v.x, v.y, v.z, v.w};
#pragma unroll
    for (int j = 0; j < 4; ++j) {
      int o = o4 * 4 + j;
      r[j] = fmaxf((r[j] - meanl[o]) * rstdl[o] * wl2[o] + bl2[o], 0.f);
    }
    *reinterpret_cast<float4*>(op + o4 * 4) =
        make_float4(r[0], r[1], r[2], r[3]);
  }
}

}  // namespace

extern "C" void kernel_launch(void* const* d_in, const int* in_sizes, int n_in,
                              void* d_out, int out_size, void* d_ws,
                              size_t ws_size, hipStream_t stream) {
  const float* x     = (const float*)d_in[0];
  const float* eattr = (const float*)d_in[1];
  const int*   eidx  = (const int*)d_in[2];
  const float* initW = (const float*)d_in[3];
  const float* initb = (const float*)d_in[4];
  const float* emW   = (const float*)d_in[5];
  const float* emb   = (const float*)d_in[6];
  const float* rW    = (const float*)d_in[7];
  const float* rb    = (const float*)d_in[8];
  const float* gnw   = (const float*)d_in[9];
  const float* gnb   = (const float*)d_in[10];
  const float* gnms  = (const float*)d_in[11];
  const float* tW    = (const float*)d_in[12];
  const float* tb    = (const float*)d_in[13];
  const float* fW    = (const float*)d_in[14];
  const float* fb    = (const float*)d_in[15];
  const float* fgw   = (const float*)d_in[16];
  const float* fgb   = (const float*)d_in[17];
  const float* fgms  = (const float*)d_in[18];
  float* out = (float*)d_out;

  // workspace layout
  float* h     = (float*)d_ws;                       // kN*kH f32
  float* conv  = h + (size_t)kN * kH;                // kN*kH f32
  float* stats = conv + (size_t)kN * kH;             // 512 f32 (4 regions x128)
  float* msg   = stats + 512;                        // kE*kH f32
  unsigned short* wbf = (unsigned short*)(msg + (size_t)kE * kH);  // 196 KB
  int* cnt    = (int*)(wbf + (size_t)kL * 64 * 64 * 8);  // kN
  int* off    = cnt + kN;                            // kN
  int* cursor = off + kN;                            // kN
  int* pos    = cursor + kN;                         // kE

  const int nodeBlocks = (kN + 63) / 64;             // 313
  const int edgeBlocks = kE / EB;                    // 1250
  const int aggBlocks  = (kN * 64 + 255) / 256;      // 5000 (wave per node)

  // one-time per call: group edges by dst, zero stats regions
  hipMemsetAsync(cnt, 0, kN * sizeof(int), stream);
  hipMemsetAsync(stats, 0, 512 * sizeof(float), stream);
  hist_dst<<<(kE + 255) / 256, 256, 0, stream>>>(eidx, cnt);
  scan_nodes<<<1, 1024, 0, stream>>>(cnt, off, cursor);
  place_edges<<<(kE + 255) / 256, 256, 0, stream>>>(eidx, cursor, pos);

  pack_w<<<kL * 64 * 64 / 256, 256, 0, stream>>>(emW, wbf);
  init_proj<<<nodeBlocks, 64, 0, stream>>>(x, initW, initb, h);
  for (int l = 0; l < kL; ++l) {
    float* st = stats + l * 128;
    edge_msg_mfma<<<edgeBlocks, 512, 0, stream>>>(
        eattr, eidx, pos, h, wbf + (size_t)l * 64 * 64 * 8,
        emb + (size_t)l * kH * kH, msg);
    agg_nodes<<<aggBlocks, 256, 0, stream>>>(msg, off, cnt, conv);
    root_stats<<<nodeBlocks, 64, 0, stream>>>(
        h, rW + (size_t)l * kH * kH, rb + l * kH, conv, st);
    norm_trans<<<nodeBlocks, 64, 0, stream>>>(
        conv, st, gnw + l * kH, gnb + l * kH, gnms + l * kH,
        tW + (size_t)l * 2 * kH * kH, tb + l * kH, h);
  }
  final_lin<<<nodeBlocks, 64, 0, stream>>>(h, fW, fb, out, stats + 3 * 128);
  final_norm<<<nodeBlocks, 64, 0, stream>>>(stats + 3 * 128, fgw, fgb, fgms,
                                            out);
}

// Round 8
// 551.083 us; speedup vs baseline: 1.0108x; 1.0108x over previous
//
#include <hip/hip_runtime.h>

namespace {

constexpr int kN  = 20000;
constexpr int kE  = 80000;
constexpr int kIn = 64;
constexpr int kH  = 32;
constexpr int kEA = 32;
constexpr int kT  = 64;
constexpr int kL  = 3;
constexpr float kEps = 1e-5f;

typedef __attribute__((ext_vector_type(8))) short bf16x8;
typedef __attribute__((ext_vector_type(4))) float f32x4;

__device__ inline unsigned short f2bf(float f) {
  unsigned u = __builtin_bit_cast(unsigned, f);
  unsigned r = (u + 0x7fff + ((u >> 16) & 1)) >> 16;  // RNE
  return (unsigned short)r;
}
__device__ inline float bf2f(unsigned short s) {
  unsigned u = ((unsigned)s) << 16;
  return __builtin_bit_cast(float, u);
}

// ---------------- edge->dst grouping: hist / scan / place ----------------
__global__ __launch_bounds__(256) void hist_dst(const int* __restrict__ ei,
                                                int* __restrict__ cnt) {
  const int e = blockIdx.x * 256 + threadIdx.x;
  if (e < kE) atomicAdd(&cnt[ei[kE + e]], 1);
}

__global__ __launch_bounds__(1024) void scan_nodes(const int* __restrict__ cnt,
                                                   int* __restrict__ off,
                                                   int* __restrict__ cursor) {
  __shared__ int buf[1024];
  __shared__ int carry_s;
  const int tid = threadIdx.x;
  if (tid == 0) carry_s = 0;
  __syncthreads();
  for (int c = 0; c < (kN + 1023) / 1024; ++c) {
    const int i = c * 1024 + tid;
    const int v = (i < kN) ? cnt[i] : 0;
    buf[tid] = v;
    __syncthreads();
    for (int s = 1; s < 1024; s <<= 1) {
      int t = 0;
      if (tid >= s) t = buf[tid - s];
      __syncthreads();
      buf[tid] += t;
      __syncthreads();
    }
    const int excl = buf[tid] - v + carry_s;
    if (i < kN) { off[i] = excl; cursor[i] = excl; }
    __syncthreads();
    if (tid == 0) carry_s += buf[1023];
    __syncthreads();
  }
}

__global__ __launch_bounds__(256) void place_edges(const int* __restrict__ ei,
                                                   int* __restrict__ cursor,
                                                   int* __restrict__ pos) {
  const int e = blockIdx.x * 256 + threadIdx.x;
  if (e < kE) pos[e] = atomicAdd(&cursor[ei[kE + e]], 1);
}

// ---- pack Wm[l] f32[32][1024] -> B-fragment-ordered bf16: frag[l][ct][lane][8]
__global__ __launch_bounds__(256) void pack_w(const float* __restrict__ emW,
                                              unsigned short* __restrict__ wbf) {
  const int idx = blockIdx.x * 256 + threadIdx.x;
  if (idx >= kL * 64 * 64) return;
  const int lane = idx & 63, ct = (idx >> 6) & 63, l = idx >> 12;
  const int k0 = (lane >> 4) * 8, c = ct * 16 + (lane & 15);
  const float* W = emW + (size_t)l * kEA * kH * kH;
  unsigned out[4];
#pragma unroll
  for (int p = 0; p < 4; ++p) {
    unsigned lo = f2bf(W[(size_t)(k0 + 2 * p) * (kH * kH) + c]);
    unsigned hi = f2bf(W[(size_t)(k0 + 2 * p + 1) * (kH * kH) + c]);
    out[p] = lo | (hi << 16);
  }
  *reinterpret_cast<uint4*>(wbf + (size_t)idx * 8) =
      make_uint4(out[0], out[1], out[2], out[3]);
}

// ---------------- h = x @ initW + initb (64-thr blocks) ----------------
__global__ __launch_bounds__(64) void init_proj(
    const float* __restrict__ x, const float* __restrict__ W,
    const float* __restrict__ b, float* __restrict__ h) {
  __shared__ float Wl[kIn * kH];
  __shared__ float bl[kH];
  const int tid = threadIdx.x;
  {
    const float4* Ws = reinterpret_cast<const float4*>(W);
    float4* Wd = reinterpret_cast<float4*>(Wl);
    for (int j = tid; j < kIn * kH / 4; j += 64) Wd[j] = Ws[j];
  }
  if (tid < kH) bl[tid] = b[tid];
  __syncthreads();
  const int node = blockIdx.x * 64 + tid;
  if (node >= kN) return;
  float xr[kIn];
  const float4* xp = reinterpret_cast<const float4*>(x + (size_t)node * kIn);
#pragma unroll
  for (int k4 = 0; k4 < kIn / 4; ++k4) {
    float4 v = xp[k4];
    xr[k4 * 4 + 0] = v.x; xr[k4 * 4 + 1] = v.y;
    xr[k4 * 4 + 2] = v.z; xr[k4 * 4 + 3] = v.w;
  }
  float* hp = h + (size_t)node * kH;
#pragma unroll
  for (int o = 0; o < kH; ++o) {
    float acc = bl[o];
#pragma unroll
    for (int k = 0; k < kIn; ++k) acc = fmaf(xr[k], Wl[k * kH + o], acc);
    hp[o] = acc;
  }
}

// ------- MFMA edge MLP + message, 2 chunks/block, pipelined staging -------
constexpr int EB  = 64;   // edges per chunk
constexpr int CPB = 2;    // chunks per block; kE = 625*128
constexpr int AP  = 40;   // attr/h LDS row pitch in ushorts (80 B)
constexpr int MP  = 36;   // msg LDS row pitch in f32 (144 B)

__device__ __forceinline__ void edge_chunk_compute(
    const unsigned short* as, const unsigned short* hs, float* ms,
    const bf16x8 (&Bf)[16], const float (&biasr)[8][2],
    int lr, int lg, int w) {
#pragma unroll
  for (int eg = 0; eg < EB / 16; ++eg) {
    bf16x8 Af = *reinterpret_cast<const bf16x8*>(as + (eg * 16 + lr) * AP + lg * 8);
    float hf[4][8];
#pragma unroll
    for (int r = 0; r < 4; ++r) {
      bf16x8 hv = *reinterpret_cast<const bf16x8*>(
          hs + (eg * 16 + lg * 4 + r) * AP + w * 8);
#pragma unroll
      for (int j = 0; j < 8; ++j) hf[r][j] = bf2f((unsigned short)hv[j]);
    }
    float ma[4][2];
#pragma unroll
    for (int r = 0; r < 4; ++r) { ma[r][0] = 0.f; ma[r][1] = 0.f; }
#pragma unroll
    for (int il = 0; il < 8; ++il) {
#pragma unroll
      for (int hh = 0; hh < 2; ++hh) {
        f32x4 c;
        c[0] = biasr[il][hh]; c[1] = biasr[il][hh];
        c[2] = biasr[il][hh]; c[3] = biasr[il][hh];
        c = __builtin_amdgcn_mfma_f32_16x16x32_bf16(Af, Bf[il * 2 + hh], c,
                                                    0, 0, 0);
#pragma unroll
        for (int r = 0; r < 4; ++r)
          ma[r][hh] = fmaf(fmaxf(c[r], 0.f), hf[r][il], ma[r][hh]);
      }
    }
#pragma unroll
    for (int r = 0; r < 4; ++r)
#pragma unroll
      for (int hh = 0; hh < 2; ++hh)
        atomicAdd(&ms[(eg * 16 + lg * 4 + r) * MP + hh * 16 + lr], ma[r][hh]);
  }
}

__global__ __launch_bounds__(256, 4) void edge_msg_mfma(
    const float* __restrict__ attr, const int* __restrict__ ei,
    const int* __restrict__ pos, const float* __restrict__ h,
    const unsigned short* __restrict__ wbf, const float* __restrict__ bm,
    float* __restrict__ msg_buf) {
  __shared__ unsigned short attr_s[CPB][EB * AP];  // 2 x 5 KB
  __shared__ unsigned short h_s[CPB][EB * AP];     // 2 x 5 KB
  __shared__ float msg_s[CPB][EB * MP];            // 2 x 9 KB
  const int tid = threadIdx.x;
  const int base = blockIdx.x * (EB * CPB);
  const int el = tid >> 2, p = tid & 3;  // 4 threads per edge, 8 floats each

  for (int j = tid; j < CPB * EB * MP; j += 256)
    (&msg_s[0][0])[j] = 0.f;

  // ---- stage chunk 0 into LDS ----
  {
    const int e = base + el;
    const int src = ei[e];
    const float4* ap =
        reinterpret_cast<const float4*>(attr + (size_t)e * kEA) + p * 2;
    const float4* hp =
        reinterpret_cast<const float4*>(h + (size_t)src * kH) + p * 2;
    float4 a0 = ap[0], a1 = ap[1];
    float4 h0 = hp[0], h1 = hp[1];
    uint2 pa0 = make_uint2(f2bf(a0.x) | ((unsigned)f2bf(a0.y) << 16),
                           f2bf(a0.z) | ((unsigned)f2bf(a0.w) << 16));
    uint2 pa1 = make_uint2(f2bf(a1.x) | ((unsigned)f2bf(a1.y) << 16),
                           f2bf(a1.z) | ((unsigned)f2bf(a1.w) << 16));
    uint2 ph0 = make_uint2(f2bf(h0.x) | ((unsigned)f2bf(h0.y) << 16),
                           f2bf(h0.z) | ((unsigned)f2bf(h0.w) << 16));
    uint2 ph1 = make_uint2(f2bf(h1.x) | ((unsigned)f2bf(h1.y) << 16),
                           f2bf(h1.z) | ((unsigned)f2bf(h1.w) << 16));
    *reinterpret_cast<uint2*>(&attr_s[0][0] + el * AP + p * 8) = pa0;
    *reinterpret_cast<uint2*>(&attr_s[0][0] + el * AP + p * 8 + 4) = pa1;
    *reinterpret_cast<uint2*>(&h_s[0][0] + el * AP + p * 8) = ph0;
    *reinterpret_cast<uint2*>(&h_s[0][0] + el * AP + p * 8 + 4) = ph1;
  }

  const int lane = tid & 63;
  const int w = tid >> 6;    // wave 0..3, owns i in [8w, 8w+8)
  const int lr = lane & 15;
  const int lg = lane >> 4;

  // hoisted per-block setup: B fragments + bias (loop-invariant)
  bf16x8 Bf[16];
#pragma unroll
  for (int t = 0; t < 16; ++t)
    Bf[t] = *reinterpret_cast<const bf16x8*>(
        wbf + ((size_t)(w * 16 + t) * 64 + lane) * 8);
  float biasr[8][2];
#pragma unroll
  for (int il = 0; il < 8; ++il)
#pragma unroll
    for (int hh = 0; hh < 2; ++hh)
      biasr[il][hh] = bm[(w * 8 + il) * kH + hh * 16 + lr];

  const int mypos0 = pos[base + el];
  const int mypos1 = pos[base + EB + el];

  // ---- issue chunk-1 global loads now; consumed after compute(0) ----
  float4 a0b, a1b, h0b, h1b;
  {
    const int e1 = base + EB + el;
    const int src1 = ei[e1];
    const float4* ap =
        reinterpret_cast<const float4*>(attr + (size_t)e1 * kEA) + p * 2;
    const float4* hp =
        reinterpret_cast<const float4*>(h + (size_t)src1 * kH) + p * 2;
    a0b = ap[0]; a1b = ap[1];
    h0b = hp[0]; h1b = hp[1];
  }

  __syncthreads();
  edge_chunk_compute(&attr_s[0][0], &h_s[0][0], &msg_s[0][0], Bf, biasr,
                     lr, lg, w);
  __syncthreads();

  // write chunk-0 messages (256 threads, 8 floats each)
  {
    float* mrow = msg_buf + (size_t)mypos0 * kH + p * 8;
    *reinterpret_cast<float4*>(mrow) =
        *reinterpret_cast<const float4*>(&msg_s[0][0] + el * MP + p * 8);
    *reinterpret_cast<float4*>(mrow + 4) =
        *reinterpret_cast<const float4*>(&msg_s[0][0] + el * MP + p * 8 + 4);
  }
  // store prefetched chunk-1 into LDS
  {
    uint2 pa0 = make_uint2(f2bf(a0b.x) | ((unsigned)f2bf(a0b.y) << 16),
                           f2bf(a0b.z) | ((unsigned)f2bf(a0b.w) << 16));
    uint2 pa1 = make_uint2(f2bf(a1b.x) | ((unsigned)f2bf(a1b.y) << 16),
                           f2bf(a1b.z) | ((unsigned)f2bf(a1b.w) << 16));
    uint2 ph0 = make_uint2(f2bf(h0b.x) | ((unsigned)f2bf(h0b.y) << 16),
                           f2bf(h0b.z) | ((unsigned)f2bf(h0b.w) << 16));
    uint2 ph1 = make_uint2(f2bf(h1b.x) | ((unsigned)f2bf(h1b.y) << 16),
                           f2bf(h1b.z) | ((unsigned)f2bf(h1b.w) << 16));
    *reinterpret_cast<uint2*>(&attr_s[1][0] + el * AP + p * 8) = pa0;
    *reinterpret_cast<uint2*>(&attr_s[1][0] + el * AP + p * 8 + 4) = pa1;
    *reinterpret_cast<uint2*>(&h_s[1][0] + el * AP + p * 8) = ph0;
    *reinterpret_cast<uint2*>(&h_s[1][0] + el * AP + p * 8 + 4) = ph1;
  }
  __syncthreads();
  edge_chunk_compute(&attr_s[1][0], &h_s[1][0], &msg_s[1][0], Bf, biasr,
                     lr, lg, w);
  __syncthreads();
  {
    float* mrow = msg_buf + (size_t)mypos1 * kH + p * 8;
    *reinterpret_cast<float4*>(mrow) =
        *reinterpret_cast<const float4*>(&msg_s[1][0] + el * MP + p * 8);
    *reinterpret_cast<float4*>(mrow + 4) =
        *reinterpret_cast<const float4*>(&msg_s[1][0] + el * MP + p * 8 + 4);
  }
}

// ------- wave-per-node segmented sum (unchanged) -------
__global__ __launch_bounds__(256) void agg_nodes(
    const float* __restrict__ msg, const int* __restrict__ off,
    const int* __restrict__ cnt, float* __restrict__ conv) {
  const int wid = (blockIdx.x * 256 + threadIdx.x) >> 6;
  const int lane = threadIdx.x & 63;
  const int col = lane & 31, half = lane >> 5;
  if (wid >= kN) return;
  const int s = off[wid], n = cnt[wid];
  float acc = 0.f;
  for (int j = half; j < n; j += 2)
    acc += msg[(size_t)(s + j) * kH + col];
  acc += __shfl_xor(acc, 32);
  if (half == 0) conv[(size_t)wid * kH + col] = acc;
}

// ------- conv += h@rootW + rootb + feature stats (64-thr blocks) -------
__global__ __launch_bounds__(64) void root_stats(
    const float* __restrict__ h, const float* __restrict__ W,
    const float* __restrict__ b, float* __restrict__ conv,
    float* __restrict__ stats) {
  __shared__ float Wl[kH * kH];
  __shared__ float bl[kH];
  __shared__ float buf[64 * (kH + 1)];
  const int tid = threadIdx.x;
  {
    const float4* Ws = reinterpret_cast<const float4*>(W);
    float4* Wd = reinterpret_cast<float4*>(Wl);
    for (int j = tid; j < kH * kH / 4; j += 64) Wd[j] = Ws[j];
  }
  if (tid < kH) bl[tid] = b[tid];
  __syncthreads();
  const int node = blockIdx.x * 64 + tid;
  const bool act = node < kN;
  float hr[kH];
  if (act) {
    const float4* hp = reinterpret_cast<const float4*>(h + (size_t)node * kH);
#pragma unroll
    for (int i4 = 0; i4 < kH / 4; ++i4) {
      float4 v = hp[i4];
      hr[i4 * 4 + 0] = v.x; hr[i4 * 4 + 1] = v.y;
      hr[i4 * 4 + 2] = v.z; hr[i4 * 4 + 3] = v.w;
    }
  } else {
#pragma unroll
    for (int i = 0; i < kH; ++i) hr[i] = 0.f;
  }
  float* cp = conv + (size_t)node * kH;
#pragma unroll
  for (int o = 0; o < kH; ++o) {
    float acc = 0.f;
    if (act) {
      acc = cp[o] + bl[o];
#pragma unroll
      for (int i = 0; i < kH; ++i) acc = fmaf(hr[i], Wl[i * kH + o], acc);
      cp[o] = acc;
    }
    buf[tid * (kH + 1) + o] = act ? acc : 0.f;
  }
  __syncthreads();
  if (tid < kH) {
    float s = 0.f, q = 0.f;
#pragma unroll 8
    for (int r = 0; r < 64; ++r) {
      float v = buf[r * (kH + 1) + tid];
      s += v;
      q = fmaf(v, v, q);
    }
    atomicAdd(stats + tid, s);
    atomicAdd(stats + kH + tid, q);
  }
}

// ---- hc = relu(graphnorm(conv))+h ; h = relu([h,hc]@transW + tb) (64-thr) ----
__global__ __launch_bounds__(64) void norm_trans(
    const float* __restrict__ conv, const float* __restrict__ stats,
    const float* __restrict__ gw, const float* __restrict__ gb,
    const float* __restrict__ gms, const float* __restrict__ Wt,
    const float* __restrict__ tb, float* __restrict__ h) {
  __shared__ float Wl[2 * kH * kH];
  __shared__ float tbl[kH];
  __shared__ float meanl[kH], rstdl[kH], gwl[kH], gbl[kH];
  const int tid = threadIdx.x;
  {
    const float4* Ws = reinterpret_cast<const float4*>(Wt);
    float4* Wd = reinterpret_cast<float4*>(Wl);
    for (int j = tid; j < 2 * kH * kH / 4; j += 64) Wd[j] = Ws[j];
  }
  if (tid < kH) {
    tbl[tid] = tb[tid];
    float m = stats[tid] * (1.f / kN);
    float q = stats[kH + tid] * (1.f / kN);
    float msv = gms[tid];
    float var = q - m * m * msv * (2.f - msv);
    meanl[tid] = msv * m;
    rstdl[tid] = rsqrtf(var + kEps);
    gwl[tid] = gw[tid];
    gbl[tid] = gb[tid];
  }
  __syncthreads();
  const int node = blockIdx.x * 64 + tid;
  if (node >= kN) return;
  float in_[2 * kH];
  const float* hp = h + (size_t)node * kH;
  const float* cp = conv + (size_t)node * kH;
#pragma unroll
  for (int i = 0; i < kH; ++i) in_[i] = hp[i];
#pragma unroll
  for (int o = 0; o < kH; ++o) {
    float v = cp[o];
    in_[kH + o] =
        fmaxf((v - meanl[o]) * rstdl[o] * gwl[o] + gbl[o], 0.f) + in_[o];
  }
  float* hw = h + (size_t)node * kH;
#pragma unroll
  for (int o = 0; o < kH; ++o) {
    float acc = tbl[o];
#pragma unroll
    for (int k = 0; k < 2 * kH; ++k) acc = fmaf(in_[k], Wl[k * kH + o], acc);
    hw[o] = fmaxf(acc, 0.f);
  }
}

// ---------- out = h @ finalW + finalb (+ stats), 64-thr blocks ----------
__global__ __launch_bounds__(64) void final_lin(
    const float* __restrict__ h, const float* __restrict__ W,
    const float* __restrict__ b, float* __restrict__ out,
    float* __restrict__ stats) {
  __shared__ float Wl[kH * kT];
  __shared__ float bl[kT];
  __shared__ float buf[64 * (kT + 1)];
  const int tid = threadIdx.x;
  {
    const float4* Ws = reinterpret_cast<const float4*>(W);
    float4* Wd = reinterpret_cast<float4*>(Wl);
    for (int j = tid; j < kH * kT / 4; j += 64) Wd[j] = Ws[j];
  }
  if (tid < kT) bl[tid] = b[tid];
  __syncthreads();
  const int node = blockIdx.x * 64 + tid;
  const bool act = node < kN;
  float hr[kH];
  if (act) {
    const float4* hp = reinterpret_cast<const float4*>(h + (size_t)node * kH);
#pragma unroll
    for (int i4 = 0; i4 < kH / 4; ++i4) {
      float4 v = hp[i4];
      hr[i4 * 4 + 0] = v.x; hr[i4 * 4 + 1] = v.y;
      hr[i4 * 4 + 2] = v.z; hr[i4 * 4 + 3] = v.w;
    }
  } else {
#pragma unroll
    for (int i = 0; i < kH; ++i) hr[i] = 0.f;
  }
  float* op = out + (size_t)node * kT;
#pragma unroll
  for (int o = 0; o < kT; ++o) {
    float acc = 0.f;
    if (act) {
      acc = bl[o];
#pragma unroll
      for (int i = 0; i < kH; ++i) acc = fmaf(hr[i], Wl[i * kT + o], acc);
      op[o] = acc;
    }
    buf[tid * (kT + 1) + o] = act ? acc : 0.f;
  }
  __syncthreads();
  if (tid < kT) {
    float s = 0.f, q = 0.f;
#pragma unroll 8
    for (int r = 0; r < 64; ++r) {
      float v = buf[r * (kT + 1) + tid];
      s += v;
      q = fmaf(v, v, q);
    }
    atomicAdd(stats + tid, s);
    atomicAdd(stats + kT + tid, q);
  }
}

// ------------- final graphnorm + relu (in place, 64-thr blocks) -------------
__global__ __launch_bounds__(64) void final_norm(
    const float* __restrict__ stats, const float* __restrict__ w,
    const float* __restrict__ b, const float* __restrict__ ms,
    float* __restrict__ out) {
  __shared__ float meanl[kT], rstdl[kT], wl2[kT], bl2[kT];
  const int tid = threadIdx.x;
  if (tid < kT) {
    float m = stats[tid] * (1.f / kN);
    float q = stats[kT + tid] * (1.f / kN);
    float msv = ms[tid];
    float var = q - m * m * msv * (2.f - msv);
    meanl[tid] = msv * m;
    rstdl[tid] = rsqrtf(var + kEps);
    wl2[tid] = w[tid];
    bl2[tid] = b[tid];
  }
  __syncthreads();
  const int node = blockIdx.x * 64 + tid;
  if (node >= kN) return;
  float* op = out + (size_t)node * kT;
#pragma unroll
  for (int o4 = 0; o4 < kT / 4; ++o4) {
    float4 v = *reinterpret_cast<const float4*>(op + o4 * 4);
    float r[4] = {v.x, v.y, v.z, v.w};
#pragma unroll
    for (int j = 0; j < 4; ++j) {
      int o = o4 * 4 + j;
      r[j] = fmaxf((r[j] - meanl[o]) * rstdl[o] * wl2[o] + bl2[o], 0.f);
    }
    *reinterpret_cast<float4*>(op + o4 * 4) =
        make_float4(r[0], r[1], r[2], r[3]);
  }
}

}  // namespace

extern "C" void kernel_launch(void* const* d_in, const int* in_sizes, int n_in,
                              void* d_out, int out_size, void* d_ws,
                              size_t ws_size, hipStream_t stream) {
  const float* x     = (const float*)d_in[0];
  const float* eattr = (const float*)d_in[1];
  const int*   eidx  = (const int*)d_in[2];
  const float* initW = (const float*)d_in[3];
  const float* initb = (const float*)d_in[4];
  const float* emW   = (const float*)d_in[5];
  const float* emb   = (const float*)d_in[6];
  const float* rW    = (const float*)d_in[7];
  const float* rb    = (const float*)d_in[8];
  const float* gnw   = (const float*)d_in[9];
  const float* gnb   = (const float*)d_in[10];
  const float* gnms  = (const float*)d_in[11];
  const float* tW    = (const float*)d_in[12];
  const float* tb    = (const float*)d_in[13];
  const float* fW    = (const float*)d_in[14];
  const float* fb    = (const float*)d_in[15];
  const float* fgw   = (const float*)d_in[16];
  const float* fgb   = (const float*)d_in[17];
  const float* fgms  = (const float*)d_in[18];
  float* out = (float*)d_out;

  // workspace layout
  float* h     = (float*)d_ws;                       // kN*kH f32
  float* conv  = h + (size_t)kN * kH;                // kN*kH f32
  float* stats = conv + (size_t)kN * kH;             // 512 f32 (4 regions x128)
  float* msg   = stats + 512;                        // kE*kH f32
  unsigned short* wbf = (unsigned short*)(msg + (size_t)kE * kH);  // 196 KB
  int* cnt    = (int*)(wbf + (size_t)kL * 64 * 64 * 8);  // kN
  int* off    = cnt + kN;                            // kN
  int* cursor = off + kN;                            // kN
  int* pos    = cursor + kN;                         // kE

  const int nodeBlocks = (kN + 63) / 64;             // 313
  const int edgeBlocks = kE / (EB * CPB);            // 625
  const int aggBlocks  = (kN * 64 + 255) / 256;      // 5000 (wave per node)

  // one-time per call: group edges by dst, zero stats regions
  hipMemsetAsync(cnt, 0, kN * sizeof(int), stream);
  hipMemsetAsync(stats, 0, 512 * sizeof(float), stream);
  hist_dst<<<(kE + 255) / 256, 256, 0, stream>>>(eidx, cnt);
  scan_nodes<<<1, 1024, 0, stream>>>(cnt, off, cursor);
  place_edges<<<(kE + 255) / 256, 256, 0, stream>>>(eidx, cursor, pos);

  pack_w<<<kL * 64 * 64 / 256, 256, 0, stream>>>(emW, wbf);
  init_proj<<<nodeBlocks, 64, 0, stream>>>(x, initW, initb, h);
  for (int l = 0; l < kL; ++l) {
    float* st = stats + l * 128;
    edge_msg_mfma<<<edgeBlocks, 256, 0, stream>>>(
        eattr, eidx, pos, h, wbf + (size_t)l * 64 * 64 * 8,
        emb + (size_t)l * kH * kH, msg);
    agg_nodes<<<aggBlocks, 256, 0, stream>>>(msg, off, cnt, conv);
    root_stats<<<nodeBlocks, 64, 0, stream>>>(
        h, rW + (size_t)l * kH * kH, rb + l * kH, conv, st);
    norm_trans<<<nodeBlocks, 64, 0, stream>>>(
        conv, st, gnw + l * kH, gnb + l * kH, gnms + l * kH,
        tW + (size_t)l * 2 * kH * kH, tb + l * kH, h);
  }
  final_lin<<<nodeBlocks, 64, 0, stream>>>(h, fW, fb, out, stats + 3 * 128);
  final_norm<<<nodeBlocks, 64, 0, stream>>>(stats + 3 * 128, fgw, fgb, fgms,
                                            out);
}

// Round 9
// 409.923 us; speedup vs baseline: 1.3588x; 1.3444x over previous
//
#include <hip/hip_runtime.h>

namespace {

constexpr int kN  = 20000;
constexpr int kE  = 80000;
constexpr int kIn = 64;
constexpr int kH  = 32;
constexpr int kEA = 32;
constexpr int kT  = 64;
constexpr int kL  = 3;
constexpr float kEps = 1e-5f;

typedef __attribute__((ext_vector_type(8))) short bf16x8;
typedef __attribute__((ext_vector_type(4))) float f32x4;

__device__ inline unsigned short f2bf(float f) {
  unsigned u = __builtin_bit_cast(unsigned, f);
  unsigned r = (u + 0x7fff + ((u >> 16) & 1)) >> 16;  // RNE
  return (unsigned short)r;
}
__device__ inline float bf2f(unsigned short s) {
  unsigned u = ((unsigned)s) << 16;
  return __builtin_bit_cast(float, u);
}

// ---------------- edge->dst grouping: hist / scan / place ----------------
__global__ __launch_bounds__(256) void hist_dst(const int* __restrict__ ei,
                                                int* __restrict__ cnt) {
  const int e = blockIdx.x * 256 + threadIdx.x;
  if (e < kE) atomicAdd(&cnt[ei[kE + e]], 1);
}

// 1 block, 1024 threads; 20 elems/thread serial + wave shfl-scan + wave combine
__global__ __launch_bounds__(1024) void scan_nodes(const int* __restrict__ cnt,
                                                   int* __restrict__ off,
                                                   int* __restrict__ cursor) {
  __shared__ int wsum[16];
  __shared__ int woff[16];
  const int tid = threadIdx.x, lane = tid & 63, wid = tid >> 6;
  constexpr int CH = 20;  // 1024*20 = 20480 >= kN
  const int base = tid * CH;
  int v[CH];
  int s = 0;
#pragma unroll
  for (int j = 0; j < CH; ++j) {
    const int i = base + j;
    const int c = (i < kN) ? cnt[i] : 0;
    v[j] = s;
    s += c;
  }
  // inclusive wave scan of s
  int x = s;
#pragma unroll
  for (int d = 1; d < 64; d <<= 1) {
    int y = __shfl_up(x, d);
    if (lane >= d) x += y;
  }
  if (lane == 63) wsum[wid] = x;
  __syncthreads();
  if (tid < 16) {
    int t = wsum[tid];
    int xx = t;
#pragma unroll
    for (int d = 1; d < 16; d <<= 1) {
      int y = __shfl_up(xx, d);
      if (tid >= d) xx += y;
    }
    woff[tid] = xx - t;  // exclusive wave base
  }
  __syncthreads();
  const int thrbase = woff[wid] + (x - s);  // exclusive thread base
#pragma unroll
  for (int j = 0; j < CH; ++j) {
    const int i = base + j;
    if (i < kN) {
      off[i] = thrbase + v[j];
      cursor[i] = thrbase + v[j];
    }
  }
}

__global__ __launch_bounds__(256) void place_edges(const int* __restrict__ ei,
                                                   int* __restrict__ cursor,
                                                   int* __restrict__ pos) {
  const int e = blockIdx.x * 256 + threadIdx.x;
  if (e < kE) pos[e] = atomicAdd(&cursor[ei[kE + e]], 1);
}

// ---- pack Wm[l] f32[32][1024] -> B-fragment-ordered bf16: frag[l][ct][lane][8]
__global__ __launch_bounds__(256) void pack_w(const float* __restrict__ emW,
                                              unsigned short* __restrict__ wbf) {
  const int idx = blockIdx.x * 256 + threadIdx.x;
  if (idx >= kL * 64 * 64) return;
  const int lane = idx & 63, ct = (idx >> 6) & 63, l = idx >> 12;
  const int k0 = (lane >> 4) * 8, c = ct * 16 + (lane & 15);
  const float* W = emW + (size_t)l * kEA * kH * kH;
  unsigned out[4];
#pragma unroll
  for (int p = 0; p < 4; ++p) {
    unsigned lo = f2bf(W[(size_t)(k0 + 2 * p) * (kH * kH) + c]);
    unsigned hi = f2bf(W[(size_t)(k0 + 2 * p + 1) * (kH * kH) + c]);
    out[p] = lo | (hi << 16);
  }
  *reinterpret_cast<uint4*>(wbf + (size_t)idx * 8) =
      make_uint4(out[0], out[1], out[2], out[3]);
}

// ---------------- h = x @ initW + initb (64-thr blocks) ----------------
__global__ __launch_bounds__(64) void init_proj(
    const float* __restrict__ x, const float* __restrict__ W,
    const float* __restrict__ b, float* __restrict__ h) {
  __shared__ float Wl[kIn * kH];
  __shared__ float bl[kH];
  const int tid = threadIdx.x;
  {
    const float4* Ws = reinterpret_cast<const float4*>(W);
    float4* Wd = reinterpret_cast<float4*>(Wl);
    for (int j = tid; j < kIn * kH / 4; j += 64) Wd[j] = Ws[j];
  }
  if (tid < kH) bl[tid] = b[tid];
  __syncthreads();
  const int node = blockIdx.x * 64 + tid;
  if (node >= kN) return;
  float xr[kIn];
  const float4* xp = reinterpret_cast<const float4*>(x + (size_t)node * kIn);
#pragma unroll
  for (int k4 = 0; k4 < kIn / 4; ++k4) {
    float4 v = xp[k4];
    xr[k4 * 4 + 0] = v.x; xr[k4 * 4 + 1] = v.y;
    xr[k4 * 4 + 2] = v.z; xr[k4 * 4 + 3] = v.w;
  }
  float* hp = h + (size_t)node * kH;
#pragma unroll
  for (int o = 0; o < kH; ++o) {
    float acc = bl[o];
#pragma unroll
    for (int k = 0; k < kIn; ++k) acc = fmaf(xr[k], Wl[k * kH + o], acc);
    hp[o] = acc;
  }
}

// ------- MFMA edge MLP + message, 2 chunks/block (setup amortized) -------
constexpr int EB  = 64;   // edges per chunk
constexpr int CPB = 2;    // chunks per block; kE = 625*128
constexpr int AP  = 40;   // attr/h LDS row pitch in ushorts (80 B)
constexpr int MP  = 36;   // msg LDS row pitch in f32 (144 B)

__device__ __forceinline__ void edge_chunk_compute(
    const unsigned short* as, const unsigned short* hs, float* ms,
    const bf16x8 (&Bf)[16], const float (&biasr)[8][2],
    int lr, int lg, int w) {
#pragma unroll
  for (int eg = 0; eg < EB / 16; ++eg) {
    bf16x8 Af = *reinterpret_cast<const bf16x8*>(as + (eg * 16 + lr) * AP + lg * 8);
    float hf[4][8];
#pragma unroll
    for (int r = 0; r < 4; ++r) {
      bf16x8 hv = *reinterpret_cast<const bf16x8*>(
          hs + (eg * 16 + lg * 4 + r) * AP + w * 8);
#pragma unroll
      for (int j = 0; j < 8; ++j) hf[r][j] = bf2f((unsigned short)hv[j]);
    }
    float ma[4][2];
#pragma unroll
    for (int r = 0; r < 4; ++r) { ma[r][0] = 0.f; ma[r][1] = 0.f; }
#pragma unroll
    for (int il = 0; il < 8; ++il) {
#pragma unroll
      for (int hh = 0; hh < 2; ++hh) {
        f32x4 c;
        c[0] = biasr[il][hh]; c[1] = biasr[il][hh];
        c[2] = biasr[il][hh]; c[3] = biasr[il][hh];
        c = __builtin_amdgcn_mfma_f32_16x16x32_bf16(Af, Bf[il * 2 + hh], c,
                                                    0, 0, 0);
#pragma unroll
        for (int r = 0; r < 4; ++r)
          ma[r][hh] = fmaf(fmaxf(c[r], 0.f), hf[r][il], ma[r][hh]);
      }
    }
#pragma unroll
    for (int r = 0; r < 4; ++r)
#pragma unroll
      for (int hh = 0; hh < 2; ++hh)
        atomicAdd(&ms[(eg * 16 + lg * 4 + r) * MP + hh * 16 + lr], ma[r][hh]);
  }
}

__device__ __forceinline__ void stage_chunk(
    const float* attr, const int* ei, const float* h, int e,
    unsigned short* attr_s, unsigned short* h_s, int el, int p) {
  const int src = ei[e];
  const float4* ap =
      reinterpret_cast<const float4*>(attr + (size_t)e * kEA) + p * 2;
  const float4* hp =
      reinterpret_cast<const float4*>(h + (size_t)src * kH) + p * 2;
  float4 a0 = ap[0], a1 = ap[1];
  float4 h0 = hp[0], h1 = hp[1];
  uint2 pa0 = make_uint2(f2bf(a0.x) | ((unsigned)f2bf(a0.y) << 16),
                         f2bf(a0.z) | ((unsigned)f2bf(a0.w) << 16));
  uint2 pa1 = make_uint2(f2bf(a1.x) | ((unsigned)f2bf(a1.y) << 16),
                         f2bf(a1.z) | ((unsigned)f2bf(a1.w) << 16));
  uint2 ph0 = make_uint2(f2bf(h0.x) | ((unsigned)f2bf(h0.y) << 16),
                         f2bf(h0.z) | ((unsigned)f2bf(h0.w) << 16));
  uint2 ph1 = make_uint2(f2bf(h1.x) | ((unsigned)f2bf(h1.y) << 16),
                         f2bf(h1.z) | ((unsigned)f2bf(h1.w) << 16));
  *reinterpret_cast<uint2*>(attr_s + el * AP + p * 8) = pa0;
  *reinterpret_cast<uint2*>(attr_s + el * AP + p * 8 + 4) = pa1;
  *reinterpret_cast<uint2*>(h_s + el * AP + p * 8) = ph0;
  *reinterpret_cast<uint2*>(h_s + el * AP + p * 8 + 4) = ph1;
}

__global__ __launch_bounds__(256) void edge_msg_mfma(
    const float* __restrict__ attr, const int* __restrict__ ei,
    const int* __restrict__ pos, const float* __restrict__ h,
    const unsigned short* __restrict__ wbf, const float* __restrict__ bm,
    float* __restrict__ msg_buf) {
  __shared__ unsigned short attr_s[EB * AP];  // 5 KB (reused both chunks)
  __shared__ unsigned short h_s[EB * AP];     // 5 KB
  __shared__ float msg_s[CPB][EB * MP];       // 18 KB (double-buffered)
  const int tid = threadIdx.x;
  const int base = blockIdx.x * (EB * CPB);
  const int el = tid >> 2, p = tid & 3;  // 4 threads/edge, 8 floats each

  for (int j = tid; j < CPB * EB * MP; j += 256) (&msg_s[0][0])[j] = 0.f;

  stage_chunk(attr, ei, h, base + el, attr_s, h_s, el, p);

  const int lane = tid & 63;
  const int w = tid >> 6;    // wave 0..3, owns i in [8w, 8w+8)
  const int lr = lane & 15;
  const int lg = lane >> 4;

  bf16x8 Bf[16];
#pragma unroll
  for (int t = 0; t < 16; ++t)
    Bf[t] = *reinterpret_cast<const bf16x8*>(
        wbf + ((size_t)(w * 16 + t) * 64 + lane) * 8);
  float biasr[8][2];
#pragma unroll
  for (int il = 0; il < 8; ++il)
#pragma unroll
    for (int hh = 0; hh < 2; ++hh)
      biasr[il][hh] = bm[(w * 8 + il) * kH + hh * 16 + lr];

  const int pos0 = pos[base + el];
  const int pos1 = pos[base + EB + el];

  __syncthreads();
  edge_chunk_compute(attr_s, h_s, &msg_s[0][0], Bf, biasr, lr, lg, w);
  __syncthreads();

  // write chunk-0 messages; restage chunk 1 into same attr/h buffers
  {
    float* mrow = msg_buf + (size_t)pos0 * kH + p * 8;
    *reinterpret_cast<float4*>(mrow) =
        *reinterpret_cast<const float4*>(&msg_s[0][0] + el * MP + p * 8);
    *reinterpret_cast<float4*>(mrow + 4) =
        *reinterpret_cast<const float4*>(&msg_s[0][0] + el * MP + p * 8 + 4);
  }
  stage_chunk(attr, ei, h, base + EB + el, attr_s, h_s, el, p);

  __syncthreads();
  edge_chunk_compute(attr_s, h_s, &msg_s[1][0], Bf, biasr, lr, lg, w);
  __syncthreads();
  {
    float* mrow = msg_buf + (size_t)pos1 * kH + p * 8;
    *reinterpret_cast<float4*>(mrow) =
        *reinterpret_cast<const float4*>(&msg_s[1][0] + el * MP + p * 8);
    *reinterpret_cast<float4*>(mrow + 4) =
        *reinterpret_cast<const float4*>(&msg_s[1][0] + el * MP + p * 8 + 4);
  }
}

// --- conv = segsum(msg) + h@rootW + rootb; stats via padded-LDS transpose ---
__global__ __launch_bounds__(256) void agg_root_stats(
    const float* __restrict__ msg, const int* __restrict__ off,
    const int* __restrict__ cnt, const float* __restrict__ h,
    const float* __restrict__ W, const float* __restrict__ b,
    float* __restrict__ conv, float* __restrict__ stats) {
  __shared__ float Wl[kH * kH];          // 4 KB
  __shared__ float bl[kH];
  __shared__ float buf[256 * (kH + 1)];  // 33 KB padded
  const int tid = threadIdx.x;
  {
    const float4* Ws = reinterpret_cast<const float4*>(W);
    float4* Wd = reinterpret_cast<float4*>(Wl);
    if (tid < kH * kH / 4) Wd[tid] = Ws[tid];
  }
  if (tid < kH) bl[tid] = b[tid];
  __syncthreads();
  const int node = blockIdx.x * 256 + tid;
  const bool act = node < kN;
  float acc[kH];
#pragma unroll
  for (int o = 0; o < kH; ++o) acc[o] = 0.f;
  if (act) {
#pragma unroll
    for (int o = 0; o < kH; ++o) acc[o] = bl[o];
    const int s = off[node], c = cnt[node];
    for (int j = 0; j < c; ++j) {
      const float4* mp =
          reinterpret_cast<const float4*>(msg + (size_t)(s + j) * kH);
#pragma unroll
      for (int o4 = 0; o4 < kH / 4; ++o4) {
        float4 v = mp[o4];
        acc[o4 * 4 + 0] += v.x; acc[o4 * 4 + 1] += v.y;
        acc[o4 * 4 + 2] += v.z; acc[o4 * 4 + 3] += v.w;
      }
    }
    float hr[kH];
    const float4* hp = reinterpret_cast<const float4*>(h + (size_t)node * kH);
#pragma unroll
    for (int i4 = 0; i4 < kH / 4; ++i4) {
      float4 v = hp[i4];
      hr[i4 * 4 + 0] = v.x; hr[i4 * 4 + 1] = v.y;
      hr[i4 * 4 + 2] = v.z; hr[i4 * 4 + 3] = v.w;
    }
#pragma unroll
    for (int o = 0; o < kH; ++o) {
      float a = acc[o];
#pragma unroll
      for (int i = 0; i < kH; ++i) a = fmaf(hr[i], Wl[i * kH + o], a);
      acc[o] = a;
    }
    float* cp = conv + (size_t)node * kH;
#pragma unroll
    for (int o4 = 0; o4 < kH / 4; ++o4)
      *reinterpret_cast<float4*>(cp + o4 * 4) =
          make_float4(acc[o4 * 4], acc[o4 * 4 + 1], acc[o4 * 4 + 2],
                      acc[o4 * 4 + 3]);
  }
#pragma unroll
  for (int o = 0; o < kH; ++o) buf[tid * (kH + 1) + o] = act ? acc[o] : 0.f;
  __syncthreads();
  if (tid < kH) {
    float s = 0.f, q = 0.f;
#pragma unroll 8
    for (int r = 0; r < 256; ++r) {
      float v = buf[r * (kH + 1) + tid];
      s += v;
      q = fmaf(v, v, q);
    }
    atomicAdd(stats + tid, s);
    atomicAdd(stats + kH + tid, q);
  }
}

// ---- hc = relu(graphnorm(conv))+h ; h = relu([h,hc]@transW + tb) (64-thr) ----
__global__ __launch_bounds__(64) void norm_trans(
    const float* __restrict__ conv, const float* __restrict__ stats,
    const float* __restrict__ gw, const float* __restrict__ gb,
    const float* __restrict__ gms, const float* __restrict__ Wt,
    const float* __restrict__ tb, float* __restrict__ h) {
  __shared__ float Wl[2 * kH * kH];
  __shared__ float tbl[kH];
  __shared__ float meanl[kH], rstdl[kH], gwl[kH], gbl[kH];
  const int tid = threadIdx.x;
  {
    const float4* Ws = reinterpret_cast<const float4*>(Wt);
    float4* Wd = reinterpret_cast<float4*>(Wl);
    for (int j = tid; j < 2 * kH * kH / 4; j += 64) Wd[j] = Ws[j];
  }
  if (tid < kH) {
    tbl[tid] = tb[tid];
    float m = stats[tid] * (1.f / kN);
    float q = stats[kH + tid] * (1.f / kN);
    float msv = gms[tid];
    float var = q - m * m * msv * (2.f - msv);
    meanl[tid] = msv * m;
    rstdl[tid] = rsqrtf(var + kEps);
    gwl[tid] = gw[tid];
    gbl[tid] = gb[tid];
  }
  __syncthreads();
  const int node = blockIdx.x * 64 + tid;
  if (node >= kN) return;
  float in_[2 * kH];
  const float* hp = h + (size_t)node * kH;
  const float* cp = conv + (size_t)node * kH;
#pragma unroll
  for (int i = 0; i < kH; ++i) in_[i] = hp[i];
#pragma unroll
  for (int o = 0; o < kH; ++o) {
    float v = cp[o];
    in_[kH + o] =
        fmaxf((v - meanl[o]) * rstdl[o] * gwl[o] + gbl[o], 0.f) + in_[o];
  }
  float* hw = h + (size_t)node * kH;
#pragma unroll
  for (int o = 0; o < kH; ++o) {
    float acc = tbl[o];
#pragma unroll
    for (int k = 0; k < 2 * kH; ++k) acc = fmaf(in_[k], Wl[k * kH + o], acc);
    hw[o] = fmaxf(acc, 0.f);
  }
}

// ---------- out = h @ finalW + finalb (+ stats), 64-thr blocks ----------
__global__ __launch_bounds__(64) void final_lin(
    const float* __restrict__ h, const float* __restrict__ W,
    const float* __restrict__ b, float* __restrict__ out,
    float* __restrict__ stats) {
  __shared__ float Wl[kH * kT];
  __shared__ float bl[kT];
  __shared__ float buf[64 * (kT + 1)];
  const int tid = threadIdx.x;
  {
    const float4* Ws = reinterpret_cast<const float4*>(W);
    float4* Wd = reinterpret_cast<float4*>(Wl);
    for (int j = tid; j < kH * kT / 4; j += 64) Wd[j] = Ws[j];
  }
  if (tid < kT) bl[tid] = b[tid];
  __syncthreads();
  const int node = blockIdx.x * 64 + tid;
  const bool act = node < kN;
  float hr[kH];
  if (act) {
    const float4* hp = reinterpret_cast<const float4*>(h + (size_t)node * kH);
#pragma unroll
    for (int i4 = 0; i4 < kH / 4; ++i4) {
      float4 v = hp[i4];
      hr[i4 * 4 + 0] = v.x; hr[i4 * 4 + 1] = v.y;
      hr[i4 * 4 + 2] = v.z; hr[i4 * 4 + 3] = v.w;
    }
  } else {
#pragma unroll
    for (int i = 0; i < kH; ++i) hr[i] = 0.f;
  }
  float* op = out + (size_t)node * kT;
#pragma unroll
  for (int o = 0; o < kT; ++o) {
    float acc = 0.f;
    if (act) {
      acc = bl[o];
#pragma unroll
      for (int i = 0; i < kH; ++i) acc = fmaf(hr[i], Wl[i * kT + o], acc);
      op[o] = acc;
    }
    buf[tid * (kT + 1) + o] = act ? acc : 0.f;
  }
  __syncthreads();
  if (tid < kT) {
    float s = 0.f, q = 0.f;
#pragma unroll 8
    for (int r = 0; r < 64; ++r) {
      float v = buf[r * (kT + 1) + tid];
      s += v;
      q = fmaf(v, v, q);
    }
    atomicAdd(stats + tid, s);
    atomicAdd(stats + kT + tid, q);
  }
}

// ------------- final graphnorm + relu (in place, 64-thr blocks) -------------
__global__ __launch_bounds__(64) void final_norm(
    const float* __restrict__ stats, const float* __restrict__ w,
    const float* __restrict__ b, const float* __restrict__ ms,
    float* __restrict__ out) {
  __shared__ float meanl[kT], rstdl[kT], wl2[kT], bl2[kT];
  const int tid = threadIdx.x;
  if (tid < kT) {
    float m = stats[tid] * (1.f / kN);
    float q = stats[kT + tid] * (1.f / kN);
    float msv = ms[tid];
    float var = q - m * m * msv * (2.f - msv);
    meanl[tid] = msv * m;
    rstdl[tid] = rsqrtf(var + kEps);
    wl2[tid] = w[tid];
    bl2[tid] = b[tid];
  }
  __syncthreads();
  const int node = blockIdx.x * 64 + tid;
  if (node >= kN) return;
  float* op = out + (size_t)node * kT;
#pragma unroll
  for (int o4 = 0; o4 < kT / 4; ++o4) {
    float4 v = *reinterpret_cast<const float4*>(op + o4 * 4);
    float r[4] = {v.x, v.y, v.z, v.w};
#pragma unroll
    for (int j = 0; j < 4; ++j) {
      int o = o4 * 4 + j;
      r[j] = fmaxf((r[j] - meanl[o]) * rstdl[o] * wl2[o] + bl2[o], 0.f);
    }
    *reinterpret_cast<float4*>(op + o4 * 4) =
        make_float4(r[0], r[1], r[2], r[3]);
  }
}

}  // namespace

extern "C" void kernel_launch(void* const* d_in, const int* in_sizes, int n_in,
                              void* d_out, int out_size, void* d_ws,
                              size_t ws_size, hipStream_t stream) {
  const float* x     = (const float*)d_in[0];
  const float* eattr = (const float*)d_in[1];
  const int*   eidx  = (const int*)d_in[2];
  const float* initW = (const float*)d_in[3];
  const float* initb = (const float*)d_in[4];
  const float* emW   = (const float*)d_in[5];
  const float* emb   = (const float*)d_in[6];
  const float* rW    = (const float*)d_in[7];
  const float* rb    = (const float*)d_in[8];
  const float* gnw   = (const float*)d_in[9];
  const float* gnb   = (const float*)d_in[10];
  const float* gnms  = (const float*)d_in[11];
  const float* tW    = (const float*)d_in[12];
  const float* tb    = (const float*)d_in[13];
  const float* fW    = (const float*)d_in[14];
  const float* fb    = (const float*)d_in[15];
  const float* fgw   = (const float*)d_in[16];
  const float* fgb   = (const float*)d_in[17];
  const float* fgms  = (const float*)d_in[18];
  float* out = (float*)d_out;

  // workspace layout
  float* h     = (float*)d_ws;                       // kN*kH f32
  float* conv  = h + (size_t)kN * kH;                // kN*kH f32
  float* stats = conv + (size_t)kN * kH;             // 512 f32 (4 regions x128)
  float* msg   = stats + 512;                        // kE*kH f32
  unsigned short* wbf = (unsigned short*)(msg + (size_t)kE * kH);  // 196 KB
  int* cnt    = (int*)(wbf + (size_t)kL * 64 * 64 * 8);  // kN
  int* off    = cnt + kN;                            // kN
  int* cursor = off + kN;                            // kN
  int* pos    = cursor + kN;                         // kE

  const int node64  = (kN + 63) / 64;                // 313
  const int node256 = (kN + 255) / 256;              // 79
  const int edgeBlocks = kE / (EB * CPB);            // 625

  hipMemsetAsync(cnt, 0, kN * sizeof(int), stream);
  hipMemsetAsync(stats, 0, 512 * sizeof(float), stream);
  hist_dst<<<(kE + 255) / 256, 256, 0, stream>>>(eidx, cnt);
  scan_nodes<<<1, 1024, 0, stream>>>(cnt, off, cursor);
  place_edges<<<(kE + 255) / 256, 256, 0, stream>>>(eidx, cursor, pos);

  pack_w<<<kL * 64 * 64 / 256, 256, 0, stream>>>(emW, wbf);
  init_proj<<<node64, 64, 0, stream>>>(x, initW, initb, h);
  for (int l = 0; l < kL; ++l) {
    float* st = stats + l * 128;
    edge_msg_mfma<<<edgeBlocks, 256, 0, stream>>>(
        eattr, eidx, pos, h, wbf + (size_t)l * 64 * 64 * 8,
        emb + (size_t)l * kH * kH, msg);
    agg_root_stats<<<node256, 256, 0, stream>>>(
        msg, off, cnt, h, rW + (size_t)l * kH * kH, rb + l * kH, conv, st);
    norm_trans<<<node64, 64, 0, stream>>>(
        conv, st, gnw + l * kH, gnb + l * kH, gnms + l * kH,
        tW + (size_t)l * 2 * kH * kH, tb + l * kH, h);
  }
  final_lin<<<node64, 64, 0, stream>>>(h, fW, fb, out, stats + 3 * 128);
  final_norm<<<node64, 64, 0, stream>>>(stats + 3 * 128, fgw, fgb, fgms, out);
}

// Round 10
// 235.903 us; speedup vs baseline: 2.3612x; 1.7377x over previous
//
#include <hip/hip_runtime.h>

namespace {

constexpr int kN  = 20000;
constexpr int kE  = 80000;
constexpr int kIn = 64;
constexpr int kH  = 32;
constexpr int kEA = 32;
constexpr int kT  = 64;
constexpr int kL  = 3;
constexpr float kEps = 1e-5f;

typedef __attribute__((ext_vector_type(8))) short bf16x8;
typedef __attribute__((ext_vector_type(4))) float f32x4;

__device__ inline unsigned short f2bf(float f) {
  unsigned u = __builtin_bit_cast(unsigned, f);
  unsigned r = (u + 0x7fff + ((u >> 16) & 1)) >> 16;  // RNE
  return (unsigned short)r;
}
__device__ inline float bf2f(unsigned short s) {
  unsigned u = ((unsigned)s) << 16;
  return __builtin_bit_cast(float, u);
}

// ---------------- edge->dst grouping: hist / scan / place ----------------
__global__ __launch_bounds__(256) void hist_dst(const int* __restrict__ ei,
                                                int* __restrict__ cnt) {
  const int e = blockIdx.x * 256 + threadIdx.x;
  if (e < kE) atomicAdd(&cnt[ei[kE + e]], 1);
}

// 1 block, 1024 threads; 20 elems/thread serial + wave shfl-scan + wave combine
__global__ __launch_bounds__(1024) void scan_nodes(const int* __restrict__ cnt,
                                                   int* __restrict__ off,
                                                   int* __restrict__ cursor) {
  __shared__ int wsum[16];
  __shared__ int woff[16];
  const int tid = threadIdx.x, lane = tid & 63, wid = tid >> 6;
  constexpr int CH = 20;  // 1024*20 = 20480 >= kN
  const int base = tid * CH;
  int v[CH];
  int s = 0;
#pragma unroll
  for (int j = 0; j < CH; ++j) {
    const int i = base + j;
    const int c = (i < kN) ? cnt[i] : 0;
    v[j] = s;
    s += c;
  }
  int x = s;
#pragma unroll
  for (int d = 1; d < 64; d <<= 1) {
    int y = __shfl_up(x, d);
    if (lane >= d) x += y;
  }
  if (lane == 63) wsum[wid] = x;
  __syncthreads();
  if (tid < 16) {
    int t = wsum[tid];
    int xx = t;
#pragma unroll
    for (int d = 1; d < 16; d <<= 1) {
      int y = __shfl_up(xx, d);
      if (tid >= d) xx += y;
    }
    woff[tid] = xx - t;
  }
  __syncthreads();
  const int thrbase = woff[wid] + (x - s);
#pragma unroll
  for (int j = 0; j < CH; ++j) {
    const int i = base + j;
    if (i < kN) {
      off[i] = thrbase + v[j];
      cursor[i] = thrbase + v[j];
    }
  }
}

__global__ __launch_bounds__(256) void place_edges(const int* __restrict__ ei,
                                                   int* __restrict__ cursor,
                                                   int* __restrict__ pos) {
  const int e = blockIdx.x * 256 + threadIdx.x;
  if (e < kE) pos[e] = atomicAdd(&cursor[ei[kE + e]], 1);
}

// ---- pack Wm[l] f32[32][1024] -> B-fragment-ordered bf16: frag[l][ct][lane][8]
__global__ __launch_bounds__(256) void pack_w(const float* __restrict__ emW,
                                              unsigned short* __restrict__ wbf) {
  const int idx = blockIdx.x * 256 + threadIdx.x;
  if (idx >= kL * 64 * 64) return;
  const int lane = idx & 63, ct = (idx >> 6) & 63, l = idx >> 12;
  const int k0 = (lane >> 4) * 8, c = ct * 16 + (lane & 15);
  const float* W = emW + (size_t)l * kEA * kH * kH;
  unsigned out[4];
#pragma unroll
  for (int p = 0; p < 4; ++p) {
    unsigned lo = f2bf(W[(size_t)(k0 + 2 * p) * (kH * kH) + c]);
    unsigned hi = f2bf(W[(size_t)(k0 + 2 * p + 1) * (kH * kH) + c]);
    out[p] = lo | (hi << 16);
  }
  *reinterpret_cast<uint4*>(wbf + (size_t)idx * 8) =
      make_uint4(out[0], out[1], out[2], out[3]);
}

// ---------------- h = x @ initW + initb (64-thr blocks) ----------------
__global__ __launch_bounds__(64) void init_proj(
    const float* __restrict__ x, const float* __restrict__ W,
    const float* __restrict__ b, float* __restrict__ h) {
  __shared__ float Wl[kIn * kH];
  __shared__ float bl[kH];
  const int tid = threadIdx.x;
  {
    const float4* Ws = reinterpret_cast<const float4*>(W);
    float4* Wd = reinterpret_cast<float4*>(Wl);
    for (int j = tid; j < kIn * kH / 4; j += 64) Wd[j] = Ws[j];
  }
  if (tid < kH) bl[tid] = b[tid];
  __syncthreads();
  const int node = blockIdx.x * 64 + tid;
  if (node >= kN) return;
  float xr[kIn];
  const float4* xp = reinterpret_cast<const float4*>(x + (size_t)node * kIn);
#pragma unroll
  for (int k4 = 0; k4 < kIn / 4; ++k4) {
    float4 v = xp[k4];
    xr[k4 * 4 + 0] = v.x; xr[k4 * 4 + 1] = v.y;
    xr[k4 * 4 + 2] = v.z; xr[k4 * 4 + 3] = v.w;
  }
  float* hp = h + (size_t)node * kH;
#pragma unroll
  for (int o = 0; o < kH; ++o) {
    float acc = bl[o];
#pragma unroll
    for (int k = 0; k < kIn; ++k) acc = fmaf(xr[k], Wl[k * kH + o], acc);
    hp[o] = acc;
  }
}

// ------- wave-independent MFMA edge MLP: 1 wave = 16 edges, all i -------
// block = 256 thr (4 waves), grid = kE/64 = 1250; ONE barrier (bias staging).
constexpr int HP  = 40;  // h LDS row pitch in ushorts (80 B)
constexpr int MPW = 36;  // msg LDS row pitch in f32 (144 B)
__global__ __launch_bounds__(256) void edge_msg_mfma(
    const float* __restrict__ attr, const int* __restrict__ ei,
    const int* __restrict__ pos, const float* __restrict__ h,
    const unsigned short* __restrict__ wbf, const float* __restrict__ bm,
    float* __restrict__ msg_buf) {
  __shared__ float bml[kH * kH];               // 4 KB, block-shared
  __shared__ unsigned short hbuf[4][16 * HP];  // 4 x 1.25 KB, wave-private
  __shared__ float mbuf[4][16 * MPW];          // 4 x 2.25 KB, wave-private
  const int tid = threadIdx.x;
  const int wv = tid >> 6, lane = tid & 63;
  const int lr = lane & 15, lg = lane >> 4;
  const int base = (blockIdx.x * 4 + wv) * 16;  // this wave's 16 edges

  for (int j = tid; j < kH * kH; j += 256) bml[j] = bm[j];

  // A into registers: lane holds attr[base+lr][lg*8 .. +8) as bf16x8
  bf16x8 Af;
  {
    const float4* ap = reinterpret_cast<const float4*>(
        attr + (size_t)(base + lr) * kEA + lg * 8);
    float4 a0 = ap[0], a1 = ap[1];
    Af[0] = (short)f2bf(a0.x); Af[1] = (short)f2bf(a0.y);
    Af[2] = (short)f2bf(a0.z); Af[3] = (short)f2bf(a0.w);
    Af[4] = (short)f2bf(a1.x); Af[5] = (short)f2bf(a1.y);
    Af[6] = (short)f2bf(a1.z); Af[7] = (short)f2bf(a1.w);
  }

  // h into wave-private LDS: lane stages edge base+(lane>>2), cols (lane&3)*8..+8
  {
    const int er = lane >> 2, q = lane & 3;
    const int src = ei[base + er];
    const float4* hp4 =
        reinterpret_cast<const float4*>(h + (size_t)src * kH + q * 8);
    float4 h0 = hp4[0], h1 = hp4[1];
    uint2 p0 = make_uint2(f2bf(h0.x) | ((unsigned)f2bf(h0.y) << 16),
                          f2bf(h0.z) | ((unsigned)f2bf(h0.w) << 16));
    uint2 p1 = make_uint2(f2bf(h1.x) | ((unsigned)f2bf(h1.y) << 16),
                          f2bf(h1.z) | ((unsigned)f2bf(h1.w) << 16));
    *reinterpret_cast<uint2*>(&hbuf[wv][0] + er * HP + q * 8) = p0;
    *reinterpret_cast<uint2*>(&hbuf[wv][0] + er * HP + q * 8 + 4) = p1;
  }

  __syncthreads();  // bml ready (hbuf is wave-private; barrier covers it too)

  float ma[4][2] = {{0.f, 0.f}, {0.f, 0.f}, {0.f, 0.f}, {0.f, 0.f}};
  const unsigned short* hrow = &hbuf[wv][0];

#pragma unroll
  for (int g = 0; g < 4; ++g) {  // il groups of 8
    bf16x8 hv0 = *reinterpret_cast<const bf16x8*>(hrow + (lg * 4 + 0) * HP + g * 8);
    bf16x8 hv1 = *reinterpret_cast<const bf16x8*>(hrow + (lg * 4 + 1) * HP + g * 8);
    bf16x8 hv2 = *reinterpret_cast<const bf16x8*>(hrow + (lg * 4 + 2) * HP + g * 8);
    bf16x8 hv3 = *reinterpret_cast<const bf16x8*>(hrow + (lg * 4 + 3) * HP + g * 8);
#pragma unroll
    for (int i8 = 0; i8 < 8; ++i8) {
      const int il = g * 8 + i8;
      bf16x8 B0 = *reinterpret_cast<const bf16x8*>(
          wbf + ((size_t)(il * 2 + 0) * 64 + lane) * 8);
      bf16x8 B1 = *reinterpret_cast<const bf16x8*>(
          wbf + ((size_t)(il * 2 + 1) * 64 + lane) * 8);
      const float b0 = bml[il * kH + lr];
      const float b1 = bml[il * kH + 16 + lr];
      f32x4 c0, c1;
      c0[0] = b0; c0[1] = b0; c0[2] = b0; c0[3] = b0;
      c1[0] = b1; c1[1] = b1; c1[2] = b1; c1[3] = b1;
      c0 = __builtin_amdgcn_mfma_f32_16x16x32_bf16(Af, B0, c0, 0, 0, 0);
      c1 = __builtin_amdgcn_mfma_f32_16x16x32_bf16(Af, B1, c1, 0, 0, 0);
      const float h0 = bf2f((unsigned short)hv0[i8]);
      const float h1 = bf2f((unsigned short)hv1[i8]);
      const float h2 = bf2f((unsigned short)hv2[i8]);
      const float h3 = bf2f((unsigned short)hv3[i8]);
      ma[0][0] = fmaf(fmaxf(c0[0], 0.f), h0, ma[0][0]);
      ma[1][0] = fmaf(fmaxf(c0[1], 0.f), h1, ma[1][0]);
      ma[2][0] = fmaf(fmaxf(c0[2], 0.f), h2, ma[2][0]);
      ma[3][0] = fmaf(fmaxf(c0[3], 0.f), h3, ma[3][0]);
      ma[0][1] = fmaf(fmaxf(c1[0], 0.f), h0, ma[0][1]);
      ma[1][1] = fmaf(fmaxf(c1[1], 0.f), h1, ma[1][1]);
      ma[2][1] = fmaf(fmaxf(c1[2], 0.f), h2, ma[2][1]);
      ma[3][1] = fmaf(fmaxf(c1[3], 0.f), h3, ma[3][1]);
    }
  }

  // epilogue: wave-private LDS transpose -> coalesced float4 stores
  float* mrow = &mbuf[wv][0];
#pragma unroll
  for (int r = 0; r < 4; ++r) {
    mrow[(lg * 4 + r) * MPW + lr] = ma[r][0];
    mrow[(lg * 4 + r) * MPW + 16 + lr] = ma[r][1];
  }
  // same-wave LDS RAW: compiler inserts lgkmcnt; no barrier needed
  {
    const int er = lane >> 2, q = lane & 3;
    const int mp = pos[base + er];
    float4 v0 = *reinterpret_cast<const float4*>(mrow + er * MPW + q * 8);
    float4 v1 = *reinterpret_cast<const float4*>(mrow + er * MPW + q * 8 + 4);
    float* orow = msg_buf + (size_t)mp * kH + q * 8;
    *reinterpret_cast<float4*>(orow) = v0;
    *reinterpret_cast<float4*>(orow + 4) = v1;
  }
}

// --- conv = segsum(msg) + h@rootW + rootb; stats via padded-LDS transpose ---
__global__ __launch_bounds__(256) void agg_root_stats(
    const float* __restrict__ msg, const int* __restrict__ off,
    const int* __restrict__ cnt, const float* __restrict__ h,
    const float* __restrict__ W, const float* __restrict__ b,
    float* __restrict__ conv, float* __restrict__ stats) {
  __shared__ float Wl[kH * kH];          // 4 KB
  __shared__ float bl[kH];
  __shared__ float buf[256 * (kH + 1)];  // 33 KB padded
  const int tid = threadIdx.x;
  {
    const float4* Ws = reinterpret_cast<const float4*>(W);
    float4* Wd = reinterpret_cast<float4*>(Wl);
    if (tid < kH * kH / 4) Wd[tid] = Ws[tid];
  }
  if (tid < kH) bl[tid] = b[tid];
  __syncthreads();
  const int node = blockIdx.x * 256 + tid;
  const bool act = node < kN;
  float acc[kH];
#pragma unroll
  for (int o = 0; o < kH; ++o) acc[o] = 0.f;
  if (act) {
#pragma unroll
    for (int o = 0; o < kH; ++o) acc[o] = bl[o];
    const int s = off[node], c = cnt[node];
    for (int j = 0; j < c; ++j) {
      const float4* mp =
          reinterpret_cast<const float4*>(msg + (size_t)(s + j) * kH);
#pragma unroll
      for (int o4 = 0; o4 < kH / 4; ++o4) {
        float4 v = mp[o4];
        acc[o4 * 4 + 0] += v.x; acc[o4 * 4 + 1] += v.y;
        acc[o4 * 4 + 2] += v.z; acc[o4 * 4 + 3] += v.w;
      }
    }
    float hr[kH];
    const float4* hp = reinterpret_cast<const float4*>(h + (size_t)node * kH);
#pragma unroll
    for (int i4 = 0; i4 < kH / 4; ++i4) {
      float4 v = hp[i4];
      hr[i4 * 4 + 0] = v.x; hr[i4 * 4 + 1] = v.y;
      hr[i4 * 4 + 2] = v.z; hr[i4 * 4 + 3] = v.w;
    }
#pragma unroll
    for (int o = 0; o < kH; ++o) {
      float a = acc[o];
#pragma unroll
      for (int i = 0; i < kH; ++i) a = fmaf(hr[i], Wl[i * kH + o], a);
      acc[o] = a;
    }
    float* cp = conv + (size_t)node * kH;
#pragma unroll
    for (int o4 = 0; o4 < kH / 4; ++o4)
      *reinterpret_cast<float4*>(cp + o4 * 4) =
          make_float4(acc[o4 * 4], acc[o4 * 4 + 1], acc[o4 * 4 + 2],
                      acc[o4 * 4 + 3]);
  }
#pragma unroll
  for (int o = 0; o < kH; ++o) buf[tid * (kH + 1) + o] = act ? acc[o] : 0.f;
  __syncthreads();
  if (tid < kH) {
    float s = 0.f, q = 0.f;
#pragma unroll 8
    for (int r = 0; r < 256; ++r) {
      float v = buf[r * (kH + 1) + tid];
      s += v;
      q = fmaf(v, v, q);
    }
    atomicAdd(stats + tid, s);
    atomicAdd(stats + kH + tid, q);
  }
}

// ---- hc = relu(graphnorm(conv))+h ; h = relu([h,hc]@transW + tb) (64-thr) ----
__global__ __launch_bounds__(64) void norm_trans(
    const float* __restrict__ conv, const float* __restrict__ stats,
    const float* __restrict__ gw, const float* __restrict__ gb,
    const float* __restrict__ gms, const float* __restrict__ Wt,
    const float* __restrict__ tb, float* __restrict__ h) {
  __shared__ float Wl[2 * kH * kH];
  __shared__ float tbl[kH];
  __shared__ float meanl[kH], rstdl[kH], gwl[kH], gbl[kH];
  const int tid = threadIdx.x;
  {
    const float4* Ws = reinterpret_cast<const float4*>(Wt);
    float4* Wd = reinterpret_cast<float4*>(Wl);
    for (int j = tid; j < 2 * kH * kH / 4; j += 64) Wd[j] = Ws[j];
  }
  if (tid < kH) {
    tbl[tid] = tb[tid];
    float m = stats[tid] * (1.f / kN);
    float q = stats[kH + tid] * (1.f / kN);
    float msv = gms[tid];
    float var = q - m * m * msv * (2.f - msv);
    meanl[tid] = msv * m;
    rstdl[tid] = rsqrtf(var + kEps);
    gwl[tid] = gw[tid];
    gbl[tid] = gb[tid];
  }
  __syncthreads();
  const int node = blockIdx.x * 64 + tid;
  if (node >= kN) return;
  float in_[2 * kH];
  const float* hp = h + (size_t)node * kH;
  const float* cp = conv + (size_t)node * kH;
#pragma unroll
  for (int i = 0; i < kH; ++i) in_[i] = hp[i];
#pragma unroll
  for (int o = 0; o < kH; ++o) {
    float v = cp[o];
    in_[kH + o] =
        fmaxf((v - meanl[o]) * rstdl[o] * gwl[o] + gbl[o], 0.f) + in_[o];
  }
  float* hw = h + (size_t)node * kH;
#pragma unroll
  for (int o = 0; o < kH; ++o) {
    float acc = tbl[o];
#pragma unroll
    for (int k = 0; k < 2 * kH; ++k) acc = fmaf(in_[k], Wl[k * kH + o], acc);
    hw[o] = fmaxf(acc, 0.f);
  }
}

// ---------- out = h @ finalW + finalb (+ stats), 64-thr blocks ----------
__global__ __launch_bounds__(64) void final_lin(
    const float* __restrict__ h, const float* __restrict__ W,
    const float* __restrict__ b, float* __restrict__ out,
    float* __restrict__ stats) {
  __shared__ float Wl[kH * kT];
  __shared__ float bl[kT];
  __shared__ float buf[64 * (kT + 1)];
  const int tid = threadIdx.x;
  {
    const float4* Ws = reinterpret_cast<const float4*>(W);
    float4* Wd = reinterpret_cast<float4*>(Wl);
    for (int j = tid; j < kH * kT / 4; j += 64) Wd[j] = Ws[j];
  }
  if (tid < kT) bl[tid] = b[tid];
  __syncthreads();
  const int node = blockIdx.x * 64 + tid;
  const bool act = node < kN;
  float hr[kH];
  if (act) {
    const float4* hp = reinterpret_cast<const float4*>(h + (size_t)node * kH);
#pragma unroll
    for (int i4 = 0; i4 < kH / 4; ++i4) {
      float4 v = hp[i4];
      hr[i4 * 4 + 0] = v.x; hr[i4 * 4 + 1] = v.y;
      hr[i4 * 4 + 2] = v.z; hr[i4 * 4 + 3] = v.w;
    }
  } else {
#pragma unroll
    for (int i = 0; i < kH; ++i) hr[i] = 0.f;
  }
  float* op = out + (size_t)node * kT;
#pragma unroll
  for (int o = 0; o < kT; ++o) {
    float acc = 0.f;
    if (act) {
      acc = bl[o];
#pragma unroll
      for (int i = 0; i < kH; ++i) acc = fmaf(hr[i], Wl[i * kT + o], acc);
      op[o] = acc;
    }
    buf[tid * (kT + 1) + o] = act ? acc : 0.f;
  }
  __syncthreads();
  if (tid < kT) {
    float s = 0.f, q = 0.f;
#pragma unroll 8
    for (int r = 0; r < 64; ++r) {
      float v = buf[r * (kT + 1) + tid];
      s += v;
      q = fmaf(v, v, q);
    }
    atomicAdd(stats + tid, s);
    atomicAdd(stats + kT + tid, q);
  }
}

// ------------- final graphnorm + relu (in place, 64-thr blocks) -------------
__global__ __launch_bounds__(64) void final_norm(
    const float* __restrict__ stats, const float* __restrict__ w,
    const float* __restrict__ b, const float* __restrict__ ms,
    float* __restrict__ out) {
  __shared__ float meanl[kT], rstdl[kT], wl2[kT], bl2[kT];
  const int tid = threadIdx.x;
  if (tid < kT) {
    float m = stats[tid] * (1.f / kN);
    float q = stats[kT + tid] * (1.f / kN);
    float msv = ms[tid];
    float var = q - m * m * msv * (2.f - msv);
    meanl[tid] = msv * m;
    rstdl[tid] = rsqrtf(var + kEps);
    wl2[tid] = w[tid];
    bl2[tid] = b[tid];
  }
  __syncthreads();
  const int node = blockIdx.x * 64 + tid;
  if (node >= kN) return;
  float* op = out + (size_t)node * kT;
#pragma unroll
  for (int o4 = 0; o4 < kT / 4; ++o4) {
    float4 v = *reinterpret_cast<const float4*>(op + o4 * 4);
    float r[4] = {v.x, v.y, v.z, v.w};
#pragma unroll
    for (int j = 0; j < 4; ++j) {
      int o = o4 * 4 + j;
      r[j] = fmaxf((r[j] - meanl[o]) * rstdl[o] * wl2[o] + bl2[o], 0.f);
    }
    *reinterpret_cast<float4*>(op + o4 * 4) =
        make_float4(r[0], r[1], r[2], r[3]);
  }
}

}  // namespace

extern "C" void kernel_launch(void* const* d_in, const int* in_sizes, int n_in,
                              void* d_out, int out_size, void* d_ws,
                              size_t ws_size, hipStream_t stream) {
  const float* x     = (const float*)d_in[0];
  const float* eattr = (const float*)d_in[1];
  const int*   eidx  = (const int*)d_in[2];
  const float* initW = (const float*)d_in[3];
  const float* initb = (const float*)d_in[4];
  const float* emW   = (const float*)d_in[5];
  const float* emb   = (const float*)d_in[6];
  const float* rW    = (const float*)d_in[7];
  const float* rb    = (const float*)d_in[8];
  const float* gnw   = (const float*)d_in[9];
  const float* gnb   = (const float*)d_in[10];
  const float* gnms  = (const float*)d_in[11];
  const float* tW    = (const float*)d_in[12];
  const float* tb    = (const float*)d_in[13];
  const float* fW    = (const float*)d_in[14];
  const float* fb    = (const float*)d_in[15];
  const float* fgw   = (const float*)d_in[16];
  const float* fgb   = (const float*)d_in[17];
  const float* fgms  = (const float*)d_in[18];
  float* out = (float*)d_out;

  // workspace layout
  float* h     = (float*)d_ws;                       // kN*kH f32
  float* conv  = h + (size_t)kN * kH;                // kN*kH f32
  float* stats = conv + (size_t)kN * kH;             // 512 f32 (4 regions x128)
  float* msg   = stats + 512;                        // kE*kH f32
  unsigned short* wbf = (unsigned short*)(msg + (size_t)kE * kH);  // 196 KB
  int* cnt    = (int*)(wbf + (size_t)kL * 64 * 64 * 8);  // kN
  int* off    = cnt + kN;                            // kN
  int* cursor = off + kN;                            // kN
  int* pos    = cursor + kN;                         // kE

  const int node64  = (kN + 63) / 64;                // 313
  const int node256 = (kN + 255) / 256;              // 79
  const int edgeBlocks = kE / 64;                    // 1250 (4 waves x 16 edges)

  hipMemsetAsync(cnt, 0, kN * sizeof(int), stream);
  hipMemsetAsync(stats, 0, 512 * sizeof(float), stream);
  hist_dst<<<(kE + 255) / 256, 256, 0, stream>>>(eidx, cnt);
  scan_nodes<<<1, 1024, 0, stream>>>(cnt, off, cursor);
  place_edges<<<(kE + 255) / 256, 256, 0, stream>>>(eidx, cursor, pos);

  pack_w<<<kL * 64 * 64 / 256, 256, 0, stream>>>(emW, wbf);
  init_proj<<<node64, 64, 0, stream>>>(x, initW, initb, h);
  for (int l = 0; l < kL; ++l) {
    float* st = stats + l * 128;
    edge_msg_mfma<<<edgeBlocks, 256, 0, stream>>>(
        eattr, eidx, pos, h, wbf + (size_t)l * 64 * 64 * 8,
        emb + (size_t)l * kH * kH, msg);
    agg_root_stats<<<node256, 256, 0, stream>>>(
        msg, off, cnt, h, rW + (size_t)l * kH * kH, rb + l * kH, conv, st);
    norm_trans<<<node64, 64, 0, stream>>>(
        conv, st, gnw + l * kH, gnb + l * kH, gnms + l * kH,
        tW + (size_t)l * 2 * kH * kH, tb + l * kH, h);
  }
  final_lin<<<node64, 64, 0, stream>>>(h, fW, fb, out, stats + 3 * 128);
  final_norm<<<node64, 64, 0, stream>>>(stats + 3 * 128, fgw, fgb, fgms, out);
}